// Round 2
// baseline (1089.182 us; speedup 1.0000x reference)
//
#include <hip/hip_runtime.h>
#include <hip/hip_bf16.h>

#define B_ 4096
#define D_ 128
#define C_ 50000
#define CPAD_ 50048          /* 391*128 */
#define NT_FULL 390
#define MT_ 32
#define S_ 64.0f
#define M0_ 0.5f
#define T_ 1.2f
#define LOSSW_ 10.0f
#define COSM0_ 0.8775825618903728f
#define SINM0_ 0.479425538604203f

typedef __attribute__((ext_vector_type(8))) short bf16x8;
typedef __attribute__((ext_vector_type(4))) float f32x4;

// ---- workspace layout (bytes) ----
#define XN_OFF    0u
#define WN_OFF    1048576u                 /* 4096*128*2 */
#define GT_OFF    (WN_OFF + 12812288u)     /* 50048*128*2 */
#define COSM_OFF  (GT_OFF + 16384u)
#define SINTH_OFF (COSM_OFF + 16384u)
#define HSUM_OFF  (SINTH_OFF + 16384u)
#define HCNT_OFF  (HSUM_OFF + 16384u)
#define HREG_OFF  (HCNT_OFF + 16384u)

// ---- output layout (floats) ----
#define OUT_HREG  ((size_t)B_ * C_)
#define OUT_GT    (OUT_HREG + 1)
#define OUT_NM    (OUT_GT + B_)
#define OUT_H     (OUT_NM + B_)

__device__ __forceinline__ unsigned short f2bf(float f) {
  unsigned u = __float_as_uint(f);
  unsigned r = (u + 0x7FFFu + ((u >> 16) & 1u)) >> 16;
  return (unsigned short)r;
}

__device__ __forceinline__ void gload_lds16(const void* g, void* l) {
  __builtin_amdgcn_global_load_lds(
      (const __attribute__((address_space(1))) void*)g,
      (__attribute__((address_space(3))) void*)l, 16, 0, 0);
}

// K1: normalize rows of x and w -> bf16, stored chunk-swizzled (j ^= row&7 per 16B chunk).
// Rows [0,B): x -> xn ; [B, B+C): w -> wn ; [B+C, B+CPAD): zero pad rows of wn.
__global__ __launch_bounds__(256) void knorm(const float* __restrict__ x,
                                             const float* __restrict__ w,
                                             unsigned short* __restrict__ xn,
                                             unsigned short* __restrict__ wn) {
  const int wave = threadIdx.x >> 6, lane = threadIdx.x & 63;
  const int row = blockIdx.x * 4 + wave;
  const int r7 = row & 7;   // B_=4096 divisible by 8, so (row-B)&7 == row&7
  float2 v = make_float2(0.f, 0.f);
  const float* src = nullptr;
  unsigned short* dst;
  if (row < B_) {
    src = x + (size_t)row * D_;
    dst = xn + (size_t)row * D_;
  } else if (row < B_ + C_) {
    src = w + (size_t)(row - B_) * D_;
    dst = wn + (size_t)(row - B_) * D_;
  } else {
    dst = wn + (size_t)(row - B_) * D_;
  }
  if (src) v = ((const float2*)src)[lane];
  float ss = v.x * v.x + v.y * v.y;
  #pragma unroll
  for (int off = 32; off > 0; off >>= 1) ss += __shfl_xor(ss, off, 64);
  float nrm = sqrtf(ss);
  float sc = (nrm > 1e-5f) ? (1.f / nrm) : 1e5f;
  if (!src) sc = 0.f;
  ushort2 o;
  o.x = f2bf(v.x * sc);
  o.y = f2bf(v.y * sc);
  const int jd = (lane >> 2) ^ r7;          // swizzled 16B-chunk index
  ((ushort2*)dst)[jd * 4 + (lane & 3)] = o;
}

// K2: exact fp32 gt / sin_theta / cos_theta_m per row; writes gt output slot.
__global__ __launch_bounds__(256) void kgt(const float* __restrict__ x,
                                           const float* __restrict__ w,
                                           const int* __restrict__ label,
                                           float* __restrict__ gtA,
                                           float* __restrict__ cosmA,
                                           float* __restrict__ sinthA,
                                           float* __restrict__ out) {
  const int wave = threadIdx.x >> 6, lane = threadIdx.x & 63;
  const int b = blockIdx.x * 4 + wave;
  const int lab = label[b];
  float2 xv = ((const float2*)(x + (size_t)b * D_))[lane];
  float2 wv = ((const float2*)(w + (size_t)lab * D_))[lane];
  float sxw = xv.x * wv.x + xv.y * wv.y;
  float sxx = xv.x * xv.x + xv.y * xv.y;
  float sww = wv.x * wv.x + wv.y * wv.y;
  #pragma unroll
  for (int off = 32; off > 0; off >>= 1) {
    sxw += __shfl_xor(sxw, off, 64);
    sxx += __shfl_xor(sxx, off, 64);
    sww += __shfl_xor(sww, off, 64);
  }
  if (lane == 0) {
    float nx = sqrtf(sxx), nw = sqrtf(sww);
    float sx = (nx > 1e-5f) ? 1.f / nx : 1e5f;
    float sw = (nw > 1e-5f) ? 1.f / nw : 1e5f;
    float g = sxw * sx * sw;
    g = fminf(1.f, fmaxf(-1.f, g));
    float st = sqrtf(fmaxf(0.f, 1.f - g * g));
    gtA[b] = g;
    sinthA[b] = st;
    cosmA[b] = g * COSM0_ - st * SINM0_;
    out[OUT_GT + b] = g;
  }
}

// K3: 128x128x128 bf16 MFMA tile; writes clip(cos)*S; accumulates per-row H partials.
template <bool FULL>
__global__ __launch_bounds__(256, 2) void kgemm(const unsigned short* __restrict__ xn,
                                                const unsigned short* __restrict__ wn,
                                                const float* __restrict__ cosmA,
                                                float* __restrict__ out,
                                                float* __restrict__ hsum,
                                                float* __restrict__ hcnt) {
  __shared__ unsigned short As[128 * 128];
  __shared__ unsigned short Bs[128 * 128];
  const int t = threadIdx.x;
  const int wave = t >> 6, lane = t & 63;
  const int lh = lane >> 4, lr = lane & 15;

  int ntile, mtile;
  if (FULL) {
    const int bid = blockIdx.x;                      // 12480 = 390*32, %8==0
    const int wg = (bid & 7) * (12480 / 8) + (bid >> 3);   // XCD-contiguous
    ntile = wg >> 5;
    mtile = wg & 31;
  } else {
    ntile = NT_FULL;
    mtile = blockIdx.x;
  }
  const int m0 = mtile * 128, n0 = ntile * 128;

  // ---- stage A,B tiles (linear LDS dest; source arrays are pre-swizzled) ----
  const char* Ag = (const char*)xn + (size_t)m0 * 256;
  const char* Bg = (const char*)wn + (size_t)n0 * 256;
  #pragma unroll
  for (int i = 0; i < 8; ++i) {
    const int q = i * 4 + wave;            // 1KB chunk id, wave-uniform
    const int srow = q * 4 + lh;
    const int sb = lr * 16;
    gload_lds16(Ag + (size_t)srow * 256 + sb, (char*)As + q * 1024);
    gload_lds16(Bg + (size_t)srow * 256 + sb, (char*)Bs + q * 1024);
  }
  __syncthreads();

  const int wr = wave >> 1, wc = wave & 1;
  f32x4 acc[4][4];
  #pragma unroll
  for (int m = 0; m < 4; ++m)
    #pragma unroll
    for (int n = 0; n < 4; ++n) acc[m][n] = (f32x4){0.f, 0.f, 0.f, 0.f};

  #pragma unroll
  for (int kk = 0; kk < 4; ++kk) {
    bf16x8 af[4], bfr[4];
    #pragma unroll
    for (int m = 0; m < 4; ++m) {
      const int row = wr * 64 + m * 16 + lr;
      const int j = (kk * 4 + lh) ^ (row & 7);
      af[m] = *(const bf16x8*)(As + row * 128 + j * 8);
    }
    #pragma unroll
    for (int n = 0; n < 4; ++n) {
      const int row = wc * 64 + n * 16 + lr;
      const int j = (kk * 4 + lh) ^ (row & 7);
      bfr[n] = *(const bf16x8*)(Bs + row * 128 + j * 8);
    }
    #pragma unroll
    for (int m = 0; m < 4; ++m)
      #pragma unroll
      for (int n = 0; n < 4; ++n)
        acc[m][n] = __builtin_amdgcn_mfma_f32_16x16x32_bf16(af[m], bfr[n], acc[m][n], 0, 0, 0);
  }

  // ---- epilogue: clip, *S, store; per-row hard-example partials ----
  #pragma unroll
  for (int m = 0; m < 4; ++m) {
    #pragma unroll
    for (int r = 0; r < 4; ++r) {
      const int grow = m0 + wr * 64 + m * 16 + lh * 4 + r;
      const float cm = cosmA[grow];
      const size_t rowbase = (size_t)grow * C_;
      float hs = 0.f, cn = 0.f;
      #pragma unroll
      for (int n = 0; n < 4; ++n) {
        const int gcol = n0 + wc * 64 + n * 16 + lr;
        if (FULL || gcol < C_) {
          float v = acc[m][n][r];
          v = fminf(1.f, fmaxf(-1.f, v));
          out[rowbase + gcol] = v * S_;
          if (v > cm) { hs += v - cm; cn += 1.f; }
        }
      }
      #pragma unroll
      for (int off = 1; off < 16; off <<= 1) {
        hs += __shfl_xor(hs, off, 64);
        cn += __shfl_xor(cn, off, 64);
      }
      if (lr == 0) atomicAdd(&hsum[grow], hs);
      else if (lr == 1) atomicAdd(&hcnt[grow], cn);
    }
  }
}

// K4: per-row finalize: remove label's contribution, H, new_m, new_gt, label fixup.
__global__ __launch_bounds__(256) void kfinal(const int* __restrict__ label,
                                              const float* __restrict__ gtA,
                                              const float* __restrict__ cosmA,
                                              const float* __restrict__ sinthA,
                                              const float* __restrict__ hsum,
                                              const float* __restrict__ hcnt,
                                              float* __restrict__ out,
                                              float* __restrict__ hregsum) {
  const int b = blockIdx.x * 256 + threadIdx.x;
  float Hv = 0.f;
  if (b < B_) {
    const int lab = label[b];
    const size_t oidx = (size_t)b * C_ + lab;
    const float cosL = out[oidx] * (1.0f / S_);
    float hs = hsum[b], cnt = hcnt[b];
    const float cm = cosmA[b];
    if (cosL > cm) { hs -= (cosL - cm); cnt -= 1.f; }
    const float num = fminf((float)C_, fmaxf(1.f, cnt));
    Hv = hs / num;
    float nm = M0_ + T_ * logf(Hv + 1.f);
    if (nm > 0.75f) nm = 0.f;
    const float cnm = cosf(nm), snm = sinf(nm);
    const float g = gtA[b], st = sinthA[b];
    const float ctm = g * cnm - st * snm;
    const float thr = -cnm;          // cos(pi - nm)
    const float mm = snm * nm;       // sin(pi - nm) * nm
    const float ngt = (g > thr) ? ctm : (g - mm);
    out[oidx] = ngt * S_;
    out[OUT_NM + b] = nm;
    out[OUT_H + b] = Hv;
  }
  __shared__ float red[256];
  red[threadIdx.x] = Hv;
  __syncthreads();
  for (int s = 128; s > 0; s >>= 1) {
    if ((int)threadIdx.x < s) red[threadIdx.x] += red[threadIdx.x + s];
    __syncthreads();
  }
  if (threadIdx.x == 0) atomicAdd(hregsum, red[0]);
}

// K5: scalar regularizer.
__global__ void khreg(float* __restrict__ out, const float* __restrict__ hregsum) {
  out[OUT_HREG] = LOSSW_ * hregsum[0] / (float)B_;
}

extern "C" void kernel_launch(void* const* d_in, const int* in_sizes, int n_in,
                              void* d_out, int out_size, void* d_ws, size_t ws_size,
                              hipStream_t stream) {
  (void)in_sizes; (void)n_in; (void)out_size; (void)ws_size;
  const float* x = (const float*)d_in[0];
  const float* w = (const float*)d_in[1];
  const int* label = (const int*)d_in[2];
  float* out = (float*)d_out;
  char* ws = (char*)d_ws;

  unsigned short* xn   = (unsigned short*)(ws + XN_OFF);
  unsigned short* wn   = (unsigned short*)(ws + WN_OFF);
  float* gtA    = (float*)(ws + GT_OFF);
  float* cosmA  = (float*)(ws + COSM_OFF);
  float* sinthA = (float*)(ws + SINTH_OFF);
  float* hsum   = (float*)(ws + HSUM_OFF);
  float* hcnt   = (float*)(ws + HCNT_OFF);
  float* hreg   = (float*)(ws + HREG_OFF);

  // zero hsum/hcnt/hreg (contiguous)
  hipMemsetAsync(ws + HSUM_OFF, 0, (2 * B_ + 1) * sizeof(float), stream);

  knorm<<<(B_ + CPAD_) / 4, 256, 0, stream>>>(x, w, xn, wn);
  kgt<<<B_ / 4, 256, 0, stream>>>(x, w, label, gtA, cosmA, sinthA, out);
  kgemm<true><<<NT_FULL * MT_, 256, 0, stream>>>(xn, wn, cosmA, out, hsum, hcnt);
  kgemm<false><<<MT_, 256, 0, stream>>>(xn, wn, cosmA, out, hsum, hcnt);
  kfinal<<<B_ / 256, 256, 0, stream>>>(label, gtA, cosmA, sinthA, hsum, hcnt, out, hreg);
  khreg<<<1, 1, 0, stream>>>(out, hreg);
}